// Round 6
// baseline (510.436 us; speedup 1.0000x reference)
//
#include <hip/hip_runtime.h>
#include <hip/hip_bf16.h>
#include <cstdint>

// B=8, C=256, N=4096 spatial self-attention.
// R5: qkv reads W from fragment-major layout (coalesced lane-linear b128);
// attn softmax max-reduction is per-row via DPP only (no ds_bpermute in the
// hot loop; better numerics than R4's wave-wide max). Skeleton as R4:
// 256 blocks x 512 thr, 32 q/wave (L/H halves), in-block 2-way key-split,
// KT=32 double-buffered global_load_lds staging.

typedef short short8 __attribute__((ext_vector_type(8)));
typedef short short4v __attribute__((ext_vector_type(4)));
typedef float f32x4 __attribute__((ext_vector_type(4)));

#define MFMA16(a, b, c) __builtin_amdgcn_mfma_f32_16x16x32_bf16((a), (b), (c), 0, 0, 0)
#define LOG2E 1.4426950408889634f

__device__ __forceinline__ unsigned short f2bf(float f) {
    union { float f; unsigned int u; } v;
    v.f = f;
    unsigned int u = v.u;
    return (unsigned short)((u + 0x7fffu + ((u >> 16) & 1u)) >> 16);
}

__device__ __forceinline__ void load_lds16(const unsigned short* g, unsigned short* l) {
    __builtin_amdgcn_global_load_lds(
        (const __attribute__((address_space(1))) unsigned int*)g,
        (__attribute__((address_space(3))) unsigned int*)l, 16, 0, 0);
}

// max over the 16-lane row group via DPP row_ror (VALU only, no LDS unit)
__device__ __forceinline__ float rowmax16_dpp(float x) {
    int v;
    v = __builtin_amdgcn_update_dpp(0, __float_as_int(x), 0x121, 0xf, 0xf, false);
    x = fmaxf(x, __int_as_float(v));
    v = __builtin_amdgcn_update_dpp(0, __float_as_int(x), 0x122, 0xf, 0xf, false);
    x = fmaxf(x, __int_as_float(v));
    v = __builtin_amdgcn_update_dpp(0, __float_as_int(x), 0x124, 0xf, 0xf, false);
    x = fmaxf(x, __int_as_float(v));
    v = __builtin_amdgcn_update_dpp(0, __float_as_int(x), 0x128, 0xf, 0xf, false);
    x = fmaxf(x, __int_as_float(v));
    return x;
}

// ---------------- Kernel 0: weight fp32 -> bf16, fragment-major --------------
// W2 chunk id = ((mat*8 + kc)*16 + cht)*64 + lane, each chunk = 8 bf16 (16 B):
// holds W[mat][ch = cht*16 + (lane&15)][k = kc*32 + (lane>>4)*8 .. +8].
// A wave reading frag (mat,kc,cht) loads W2 + frag*512 + lane*8: coalesced 1KB.
__global__ __launch_bounds__(256) void wcvt_kernel(
    const float* __restrict__ wq, const float* __restrict__ wk,
    const float* __restrict__ wv, unsigned short* __restrict__ W2)
{
    int gid = blockIdx.x * 256 + threadIdx.x;     // 0..24575
    int lane = gid & 63;
    int cht  = (gid >> 6) & 15;
    int kc   = (gid >> 10) & 7;
    int mat  = gid >> 13;
    const float* src = (mat == 0) ? wq : ((mat == 1) ? wk : wv);
    int ch = cht * 16 + (lane & 15);
    int k  = kc * 32 + ((lane >> 4) & 3) * 8;
    const float* s = src + ch * 256 + k;
    float4 f0 = *(const float4*)(s);
    float4 f1 = *(const float4*)(s + 4);
    short8 o = { (short)f2bf(f0.x), (short)f2bf(f0.y), (short)f2bf(f0.z), (short)f2bf(f0.w),
                 (short)f2bf(f1.x), (short)f2bf(f1.y), (short)f2bf(f1.z), (short)f2bf(f1.w) };
    *(short8*)(W2 + (size_t)gid * 8) = o;
}

// ---------------- Kernel 1: QKV projection via MFMA --------------------------
// 1024 blocks x 256 thr (4 waves). Block: batch b, 32 tokens; wave: 64 channels.
// Qc [B][C][N] (pre-scaled by log2e), Kr [B][N][C], Vc [B][C][N].
__global__ __launch_bounds__(256, 2) void qkv_kernel(
    const float* __restrict__ x, const unsigned short* __restrict__ W2,
    const float* __restrict__ bq, const float* __restrict__ bk,
    const float* __restrict__ bv,
    unsigned short* __restrict__ Qc, unsigned short* __restrict__ Kr,
    unsigned short* __restrict__ Vc)
{
    const int C = 256, N = 4096;
    __shared__ __align__(16) unsigned short Xt[32][264];   // [token][c], pad 264

    const int tid  = threadIdx.x;
    const int bid  = blockIdx.x;
    const int b    = bid >> 7;
    const int n0   = (bid & 127) * 32;
    const int wave = tid >> 6;
    const int lane = tid & 63;
    const int quad = lane >> 4;
    const int l16  = lane & 15;
    const int ch0  = wave * 64;

    // stage X^T tile: fp32 [c][token] -> bf16 LDS [token][c]
    {
        const int token = tid & 31;
        const int cg    = tid >> 5;
        const float* xb = x + ((size_t)b * C) * N + n0 + token;
#pragma unroll
        for (int p = 0; p < 8; p++) {
            int c0 = p * 32 + cg * 4;
            float f0 = xb[(size_t)(c0 + 0) * N];
            float f1 = xb[(size_t)(c0 + 1) * N];
            float f2 = xb[(size_t)(c0 + 2) * N];
            float f3 = xb[(size_t)(c0 + 3) * N];
            short4v s = { (short)f2bf(f0), (short)f2bf(f1), (short)f2bf(f2), (short)f2bf(f3) };
            *(short4v*)(&Xt[token][c0]) = s;
        }
    }
    __syncthreads();

    f32x4 acc[3][4][2];
#pragma unroll
    for (int m = 0; m < 3; m++)
#pragma unroll
        for (int ct = 0; ct < 4; ct++)
#pragma unroll
            for (int tt = 0; tt < 2; tt++) acc[m][ct][tt] = (f32x4){0.f, 0.f, 0.f, 0.f};

#pragma unroll
    for (int kc = 0; kc < 8; kc++) {
        const int ko = kc * 32 + quad * 8;
        short8 ax0 = *(const short8*)(&Xt[l16][ko]);
        short8 ax1 = *(const short8*)(&Xt[16 + l16][ko]);
#pragma unroll
        for (int m = 0; m < 3; m++) {
#pragma unroll
            for (int ct = 0; ct < 4; ct++) {
                // fragment-major: coalesced lane-linear load
                int frag = ((m * 8 + kc) * 16 + wave * 4 + ct);
                short8 wf = *(const short8*)(W2 + (size_t)frag * 512 + lane * 8);
                acc[m][ct][0] = MFMA16(ax0, wf, acc[m][ct][0]);
                acc[m][ct][1] = MFMA16(ax1, wf, acc[m][ct][1]);
            }
        }
    }

    // ---- Q (scaled by log2e) and V: b64 stores to [C][N]
#pragma unroll
    for (int ct = 0; ct < 4; ct++) {
        const int ch = ch0 + ct * 16 + l16;
        const float biq = bq[ch], biv = bv[ch];
#pragma unroll
        for (int tt = 0; tt < 2; tt++) {
            const int tok0 = n0 + tt * 16 + quad * 4;
            short4v qs = { (short)f2bf((acc[0][ct][tt][0] + biq) * LOG2E),
                           (short)f2bf((acc[0][ct][tt][1] + biq) * LOG2E),
                           (short)f2bf((acc[0][ct][tt][2] + biq) * LOG2E),
                           (short)f2bf((acc[0][ct][tt][3] + biq) * LOG2E) };
            *(short4v*)(Qc + ((size_t)b * C + ch) * N + tok0) = qs;
            short4v vs = { (short)f2bf(acc[2][ct][tt][0] + biv),
                           (short)f2bf(acc[2][ct][tt][1] + biv),
                           (short)f2bf(acc[2][ct][tt][2] + biv),
                           (short)f2bf(acc[2][ct][tt][3] + biv) };
            *(short4v*)(Vc + ((size_t)b * C + ch) * N + tok0) = vs;
        }
    }

    // ---- K: transpose via LDS -> coalesced [N][C] b128 stores
    __syncthreads();    // Xt reads all done
#pragma unroll
    for (int ct = 0; ct < 4; ct++) {
        const int ch = ch0 + ct * 16 + l16;
        const float bik = bk[ch];
#pragma unroll
        for (int tt = 0; tt < 2; tt++) {
#pragma unroll
            for (int r = 0; r < 4; r++)
                Xt[tt * 16 + quad * 4 + r][ch] = f2bf(acc[1][ct][tt][r] + bik);
        }
    }
    __syncthreads();
#pragma unroll
    for (int p = 0; p < 2; p++) {
        int chunk = p * 256 + tid;          // 0..511
        int tok = chunk >> 4;
        int cc  = (chunk & 15) * 16;
        *(short8*)(Kr + ((size_t)b * N + n0 + tok) * C + cc) = *(const short8*)(&Xt[tok][cc]);
    }
}

// ---------------- Kernel 2: flash attention + epilogue -----------------------
// 256 blocks x 512 thr (8 waves, 2/SIMD — register-capped). b = bid&7.
// Wave w: queries q0 = qblk + (w&3)*32 (halves L/H of 16), keys
// [(w>>2)*2048, +2048) in 64 iters of KT=32. In-block LDS merge at end.
// Fragment layouts (gfx950, verified):
//   A[m=lane&15][k=quad*8+j]  B[n=lane&15][k=quad*8+j]  C/D[row=quad*4+r][col=lane&15]
__global__ __launch_bounds__(512, 2) void attn_kernel(
    const unsigned short* __restrict__ Qc,
    const unsigned short* __restrict__ Kr,
    const unsigned short* __restrict__ Vc,
    const float* __restrict__ x,
    const float* __restrict__ gamma,
    float* __restrict__ out)
{
    const int C = 256, N = 4096;
    __shared__ __align__(16) unsigned short KV[2][32768];   // 128 KB
    __shared__ __align__(16) unsigned short Pt[8][1280];    // 32 rows x 40
    __shared__ float MlL[4][32];
    __shared__ float MmL[4][32];

    const int tid  = threadIdx.x;
    const int wave = tid >> 6;
    const int ks   = wave >> 2;          // key-split half
    const int w4   = wave & 3;
    const int lane = tid & 63;
    const int quad = lane >> 4;
    const int l16  = lane & 15;
    const int bid  = blockIdx.x;
    const int b    = bid & 7;
    const int q0   = (bid >> 3) * 128 + w4 * 32;

    const unsigned short* kb  = Kr + (size_t)b * N * C;
    const unsigned short* vcb = Vc + (size_t)b * C * N;

    // Q A-fragments (scalar loads from [C][N], once per kernel)
    short8 aqL[8], aqH[8];
    {
        const unsigned short* qb = Qc + (size_t)b * C * N + q0 + l16;
#pragma unroll
        for (int f = 0; f < 8; f++) {
#pragma unroll
            for (int j = 0; j < 8; j++) {
                size_t co = (size_t)(f * 32 + quad * 8 + j) * N;
                aqL[f][j] = (short)qb[co];
                aqH[f][j] = (short)qb[co + 16];
            }
        }
    }

    f32x4 oL[16], oH[16];
#pragma unroll
    for (int t = 0; t < 16; t++) {
        oL[t] = (f32x4){0.f, 0.f, 0.f, 0.f};
        oH[t] = (f32x4){0.f, 0.f, 0.f, 0.f};
    }
    float m_r[2][4], l_p[2][4];
#pragma unroll
    for (int h = 0; h < 2; h++)
#pragma unroll
        for (int r = 0; r < 4; r++) { m_r[h][r] = -__builtin_inff(); l_p[h][r] = 0.f; }

    // stage both key-halves' K/V tiles (block-wide)
    auto stage = [&](int buf, int m0) {
        unsigned short* dst = &KV[buf][0];
#pragma unroll
        for (int p = 0; p < 4; p++) {               // K: 2048 chunks
            int chunk = p * 512 + tid;
            int half = chunk >> 10;
            int idx  = chunk & 1023;
            int key = idx >> 5;
            int j = (idx & 31) ^ (key & 31);
            load_lds16(kb + (size_t)(half * 2048 + m0 + key) * C + j * 8,
                       dst + half * 16384 + idx * 8);
        }
#pragma unroll
        for (int p = 0; p < 4; p++) {               // V: 2048 chunks
            int chunk = p * 512 + tid;
            int half = chunk >> 10;
            int idx  = chunk & 1023;
            int c = idx >> 2;
            int j = (idx & 3) ^ (c & 3);
            load_lds16(vcb + (size_t)c * N + half * 2048 + m0 + j * 8,
                       dst + half * 16384 + 8192 + idx * 8);
        }
    };

    stage(0, 0);
    __syncthreads();

    unsigned short* PtW = &Pt[wave][0];

    for (int it = 0; it < 64; ++it) {
        const int cur = it & 1;
        if (it < 63) stage(cur ^ 1, (it + 1) * 32);

        const unsigned short* Kb = &KV[cur][ks * 16384];
        const unsigned short* Vb = Kb + 8192;

        // ---- S = Q K^T : 32 queries x 32 keys
        f32x4 sL0 = {0.f,0.f,0.f,0.f}, sL1 = {0.f,0.f,0.f,0.f};
        f32x4 sH0 = {0.f,0.f,0.f,0.f}, sH1 = {0.f,0.f,0.f,0.f};
#pragma unroll
        for (int f = 0; f < 8; f++) {
            const int j = f * 4 + quad;
            int k0 = l16, k1 = 16 + l16;
            short8 kf0 = *(const short8*)(Kb + (k0 * 32 + (j ^ (k0 & 31))) * 8);
            short8 kf1 = *(const short8*)(Kb + (k1 * 32 + (j ^ (k1 & 31))) * 8);
            sL0 = MFMA16(aqL[f], kf0, sL0);
            sL1 = MFMA16(aqL[f], kf1, sL1);
            sH0 = MFMA16(aqH[f], kf0, sH0);
            sH1 = MFMA16(aqH[f], kf1, sH1);
        }

        // ---- per-row online softmax (base-2), DPP-only max reduction
        float aLr[4], aHr[4];
        bool anyup = false;
#pragma unroll
        for (int r = 0; r < 4; r++) {
            {
                float mx = rowmax16_dpp(fmaxf(sL0[r], sL1[r]));
                float mn = fmaxf(m_r[0][r], mx);
                anyup |= (mn > m_r[0][r]);
                float al = exp2f(m_r[0][r] - mn);
                m_r[0][r] = mn;
                aLr[r] = al;
                float e0 = exp2f(sL0[r] - mn);
                float e1 = exp2f(sL1[r] - mn);
                l_p[0][r] = l_p[0][r] * al + (e0 + e1);
                union { __hip_bfloat162 v; unsigned int u; } cv;
                cv.v = __float22bfloat162_rn(float2{e0, e1});
                unsigned short* pr = PtW + (quad * 4 + r) * 40 + l16;
                pr[0]  = (unsigned short)(cv.u & 0xffff);
                pr[16] = (unsigned short)(cv.u >> 16);
            }
            {
                float mx = rowmax16_dpp(fmaxf(sH0[r], sH1[r]));
                float mn = fmaxf(m_r[1][r], mx);
                anyup |= (mn > m_r[1][r]);
                float al = exp2f(m_r[1][r] - mn);
                m_r[1][r] = mn;
                aHr[r] = al;
                float e0 = exp2f(sH0[r] - mn);
                float e1 = exp2f(sH1[r] - mn);
                l_p[1][r] = l_p[1][r] * al + (e0 + e1);
                union { __hip_bfloat162 v; unsigned int u; } cv;
                cv.v = __float22bfloat162_rn(float2{e0, e1});
                unsigned short* pr = PtW + (16 + quad * 4 + r) * 40 + l16;
                pr[0]  = (unsigned short)(cv.u & 0xffff);
                pr[16] = (unsigned short)(cv.u >> 16);
            }
        }
        if (__any(anyup)) {
            f32x4 aLv = (f32x4){aLr[0], aLr[1], aLr[2], aLr[3]};
            f32x4 aHv = (f32x4){aHr[0], aHr[1], aHr[2], aHr[3]};
#pragma unroll
            for (int t = 0; t < 16; t++) { oL[t] *= aLv; oH[t] *= aHv; }
        }

        // ---- P -> A-layout (wave-private LDS)
        short8 apL = *(const short8*)(PtW + l16 * 40 + quad * 8);
        short8 apH = *(const short8*)(PtW + (16 + l16) * 40 + quad * 8);

        // ---- PV: 16 channel-tiles, each V fragment feeds both halves
#pragma unroll
        for (int t = 0; t < 16; t++) {
            int c = t * 16 + l16;
            short8 vf = *(const short8*)(Vb + (c * 4 + (quad ^ (c & 3))) * 8);
            oL[t] = MFMA16(apL, vf, oL[t]);
            oH[t] = MFMA16(apH, vf, oH[t]);
        }
        __syncthreads();
    }

    // ---- reduce l partials over the 16-lane row group
#pragma unroll
    for (int h = 0; h < 2; h++)
#pragma unroll
        for (int r = 0; r < 4; r++) {
            float rs = l_p[h][r];
            rs += __shfl_xor(rs, 1);
            rs += __shfl_xor(rs, 2);
            rs += __shfl_xor(rs, 4);
            rs += __shfl_xor(rs, 8);
            l_p[h][r] = rs;
        }

    // ---- in-block merge of the two key-halves
    float* CombF = (float*)(&KV[0][0]);   // 4 waves x 32 q x 256 c f32 = 128 KB
    __syncthreads();
    if (ks == 1) {
#pragma unroll
        for (int t = 0; t < 16; t++) {
#pragma unroll
            for (int r = 0; r < 4; r++) {
                CombF[(size_t)(w4 * 32 + quad * 4 + r) * 256 + t * 16 + l16] = oL[t][r];
                CombF[(size_t)(w4 * 32 + 16 + quad * 4 + r) * 256 + t * 16 + l16] = oH[t][r];
            }
        }
        if (l16 == 0) {
#pragma unroll
            for (int h = 0; h < 2; h++)
#pragma unroll
                for (int r = 0; r < 4; r++) {
                    MlL[w4][h * 16 + quad * 4 + r] = l_p[h][r];
                    MmL[w4][h * 16 + quad * 4 + r] = m_r[h][r];
                }
        }
    }
    __syncthreads();
    if (ks == 0) {
        const float g = gamma[0];
        float f1v[2][4], f2v[2][4], linv[2][4];
#pragma unroll
        for (int h = 0; h < 2; h++)
#pragma unroll
            for (int r = 0; r < 4; r++) {
                float m2 = MmL[w4][h * 16 + quad * 4 + r];
                float l2 = MlL[w4][h * 16 + quad * 4 + r];
                float mt = fmaxf(m_r[h][r], m2);
                float f1 = exp2f(m_r[h][r] - mt);
                float f2 = exp2f(m2 - mt);
                f1v[h][r] = f1;
                f2v[h][r] = f2;
                linv[h][r] = g / (l_p[h][r] * f1 + l2 * f2);
            }
#pragma unroll
        for (int t = 0; t < 16; t++) {
            const int c = t * 16 + l16;
#pragma unroll
            for (int h = 0; h < 2; h++) {
                const int nb = q0 + h * 16 + quad * 4;
                f32x4 o1 = h ? oH[t] : oL[t];
                f32x4 ov;
#pragma unroll
                for (int r = 0; r < 4; r++) {
                    float o2 = CombF[(size_t)(w4 * 32 + h * 16 + quad * 4 + r) * 256 + c];
                    ov[r] = (o1[r] * f1v[h][r] + o2 * f2v[h][r]) * linv[h][r];
                }
                size_t idx = ((size_t)(b * C + c)) * N + nb;
                f32x4 xv = *(const f32x4*)(x + idx);
                *(f32x4*)(out + idx) = ov + xv;
            }
        }
    }
}

extern "C" void kernel_launch(void* const* d_in, const int* in_sizes, int n_in,
                              void* d_out, int out_size, void* d_ws, size_t ws_size,
                              hipStream_t stream) {
    const int B = 8, C = 256, N = 4096;
    const float* x     = (const float*)d_in[0];
    const float* wq    = (const float*)d_in[1];
    const float* bq    = (const float*)d_in[2];
    const float* wk    = (const float*)d_in[3];
    const float* bk    = (const float*)d_in[4];
    const float* wv    = (const float*)d_in[5];
    const float* bv    = (const float*)d_in[6];
    const float* gamma = (const float*)d_in[7];
    float* out = (float*)d_out;

    unsigned short* Qc = (unsigned short*)d_ws;             // [B][C][N] bf16 (x log2e)
    unsigned short* Kr = Qc + (size_t)B * C * N;            // [B][N][C] bf16
    unsigned short* Vc = Kr + (size_t)B * N * C;            // [B][C][N] bf16
    unsigned short* W2 = Vc + (size_t)B * C * N;            // [3*8*16*64*8] bf16

    wcvt_kernel<<<dim3(96), 256, 0, stream>>>(wq, wk, wv, W2);
    qkv_kernel<<<dim3(1024), 256, 0, stream>>>(x, W2, bq, bk, bv, Qc, Kr, Vc);
    attn_kernel<<<dim3(256), 512, 0, stream>>>(Qc, Kr, Vc, x, gamma, out);
}